// Round 20
// baseline (320.563 us; speedup 1.0000x reference)
//
#include <hip/hip_runtime.h>
#include <hip/hip_bf16.h>
#include <stdint.h>

#define T_TOK 1024
#define HDIM  1024
#define NEXP  16
#define IDIM  2880
#define GU_COLS (2*IDIM)   // 5760
#define TOPK  4
#define ESTRIDE ((size_t)T_TOK * TOPK * HDIM)   // 4096*1024 floats per eo buffer

using short4v  = __attribute__((ext_vector_type(4))) short;
using short8   = __attribute__((ext_vector_type(8))) short;
using ushort4v = __attribute__((ext_vector_type(4))) unsigned short;
using f32x4    = __attribute__((ext_vector_type(4))) float;

__device__ __forceinline__ unsigned short f2b(float f) {
    union { float f; unsigned u; } x; x.f = f;
    unsigned r = x.u + 0x7FFFu + ((x.u >> 16) & 1u);  // RNE
    return (unsigned short)(r >> 16);
}

typedef const __attribute__((address_space(1))) unsigned int* gas1_t;
typedef __attribute__((address_space(3))) unsigned int* las3_t;
__device__ __forceinline__ void gload16(const void* g, void* l) {
    __builtin_amdgcn_global_load_lds((gas1_t)g, (las3_t)l, 16, 0, 0);
}

// ---------------- Kernel 1: router + x->bf16 --------------------------------
__global__ __launch_bounds__(256) void router_kernel(
    const float* __restrict__ x, const float* __restrict__ gw,
    const float* __restrict__ gb, float* __restrict__ logits_out,
    int* __restrict__ counts, int* __restrict__ lists, float* __restrict__ wts,
    int* __restrict__ tokslot4, float* __restrict__ wts4,
    unsigned short* __restrict__ xb)
{
    int t = blockIdx.x;
    int tid = threadIdx.x;
    const float* xr = x + (size_t)t * HDIM;
    {
        float4 v = *(const float4*)(xr + tid * 4);
        ushort4v b; b.x = f2b(v.x); b.y = f2b(v.y); b.z = f2b(v.z); b.w = f2b(v.w);
        *(ushort4v*)(xb + (size_t)t * HDIM + tid * 4) = b;
    }
    int e = tid >> 4;
    int l16 = tid & 15;
    const float* wr = gw + (size_t)e * HDIM;
    float p = 0.f;
    for (int h = l16; h < HDIM; h += 16) p += xr[h] * wr[h];
    p += __shfl_xor(p, 8);
    p += __shfl_xor(p, 4);
    p += __shfl_xor(p, 2);
    p += __shfl_xor(p, 1);
    __shared__ float sl[NEXP];
    if (l16 == 0) {
        float v = p + gb[e];
        sl[e] = v;
        logits_out[t * NEXP + e] = v;
    }
    __syncthreads();
    if (tid == 0) {
        float v[NEXP];
#pragma unroll
        for (int i = 0; i < NEXP; ++i) v[i] = sl[i];
        int idx[TOPK]; float tv[TOPK];
        unsigned used = 0;
#pragma unroll
        for (int k = 0; k < TOPK; ++k) {
            float best = -__builtin_inff(); int bi = 0;
#pragma unroll
            for (int i = 0; i < NEXP; ++i)
                if (!((used >> i) & 1u) && v[i] > best) { best = v[i]; bi = i; }
            used |= 1u << bi; idx[k] = bi; tv[k] = best;
        }
        float m = tv[0];
        float ex[TOPK], s = 0.f;
#pragma unroll
        for (int k = 0; k < TOPK; ++k) { ex[k] = expf(tv[k] - m); s += ex[k]; }
#pragma unroll
        for (int k = 0; k < TOPK; ++k) {
            float w = ex[k] / s;
            int slot = atomicAdd(&counts[idx[k]], 1);
            lists[idx[k] * T_TOK + slot] = t;
            wts[idx[k] * T_TOK + slot] = w;
            tokslot4[t * TOPK + k] = (idx[k] << 16) | slot;
            wts4[t * TOPK + k] = w;
        }
    }
}

// ---------------- Kernel 2: exclusive prefix sum ---------------------------
__global__ void offsets_kernel(const int* __restrict__ counts, int* __restrict__ offsets)
{
    if (threadIdx.x == 0) {
        int o = 0;
        for (int e = 0; e < NEXP; ++e) { offsets[e] = o; o += counts[e]; }
        offsets[NEXP] = o;
    }
}

// ---------------- Kernel 3: gate_up GEMM + silu ----------------------------
// Round-12 best structure (unchanged). XCD-CLUSTERED decode: xcd = e&7.
__global__ __launch_bounds__(512) void gu_kernel(
    const unsigned short* __restrict__ xb, const float* __restrict__ gup,
    const float* __restrict__ gub, const int* __restrict__ counts,
    const int* __restrict__ offsets, const int* __restrict__ lists,
    unsigned short* __restrict__ inter)
{
    int bid = blockIdx.x;
    int xcd = bid & 7;
    int r   = bid >> 3;          // 0..719
    int nt  = r % 90;
    int s   = r / 90;            // 0..7
    int e   = xcd + ((s & 1) << 3);
    int mt  = s >> 1;            // 0..3
    int ne = counts[e];
    if (mt * 256 >= ne) return;

    int tid = threadIdx.x;
    int wave = tid >> 6, lane = tid & 63;
    int l16 = lane & 15, lq = lane >> 4;

    __shared__ int tokid[256];
    __shared__ unsigned short As[256 * 64];   // 32 KB
    __shared__ unsigned short Bs[64 * 64];    // 8 KB

    if (tid < 256) {
        int slot = mt * 256 + tid;
        tokid[tid] = (slot < ne) ? lists[e * T_TOK + slot] : lists[e * T_TOK];
    }
    __syncthreads();

    const float* gup_e = gup + (size_t)e * HDIM * GU_COLS;

    int at = tid - 256;
    const unsigned short* asrc[8];
    if (tid >= 256) {
#pragma unroll
        for (int i = 0; i < 8; ++i) {
            int s2 = at + i * 256;
            int row = s2 >> 3, c = s2 & 7;
            asrc[i] = xb + (size_t)tokid[row] * HDIM + ((c ^ (row & 7)) * 8);
        }
    }
    int nb = tid & 15, kb = tid >> 4;
    const float* bsrc = nullptr;
    if (tid < 256) {
        int n0 = nb * 4;
        size_t col = (n0 < 32) ? (size_t)(nt * 32 + n0) : (size_t)(IDIM + nt * 32 + (n0 - 32));
        bsrc = gup_e + (size_t)(kb * 4) * GU_COLS + col;
    }

    f32x4 acc[2][4];
#pragma unroll
    for (int i = 0; i < 2; ++i)
#pragma unroll
        for (int f = 0; f < 4; ++f) acc[i][f] = (f32x4){0.f, 0.f, 0.f, 0.f};

    float4 br0, br1, br2, br3;
    if (tid < 256) {
        br0 = *(const float4*)(bsrc);
        br1 = *(const float4*)(bsrc + GU_COLS);
        br2 = *(const float4*)(bsrc + 2 * GU_COLS);
        br3 = *(const float4*)(bsrc + 3 * GU_COLS);
    }

    for (int kk = 0; kk < HDIM; kk += 64) {
        __syncthreads();
        if (tid >= 256) {
#pragma unroll
            for (int i = 0; i < 8; ++i)
                gload16(asrc[i] + kk, As + ((size_t)(at + i * 256)) * 8);
        } else {
#pragma unroll
            for (int j = 0; j < 4; ++j) {
                int n = nb * 4 + j;
                int slot = kb ^ (n & 15);
                ushort4v b;
                b.x = f2b((&br0.x)[j]); b.y = f2b((&br1.x)[j]);
                b.z = f2b((&br2.x)[j]); b.w = f2b((&br3.x)[j]);
                *(ushort4v*)&Bs[n * 64 + slot * 4] = b;
            }
        }
        __syncthreads();
        if (tid < 256 && kk + 64 < HDIM) {
            const float* sp = bsrc + (size_t)(kk + 64) * GU_COLS;
            br0 = *(const float4*)(sp);
            br1 = *(const float4*)(sp + GU_COLS);
            br2 = *(const float4*)(sp + 2 * GU_COLS);
            br3 = *(const float4*)(sp + 3 * GU_COLS);
        }
        __builtin_amdgcn_s_setprio(1);
#pragma unroll
        for (int ks = 0; ks < 2; ++ks) {
            short8 a[2], b[4];
#pragma unroll
            for (int i = 0; i < 2; ++i) {
                int row = wave * 32 + i * 16 + l16;
                int q = ks * 4 + lq;
                a[i] = *(const short8*)&As[row * 64 + ((q ^ (row & 7)) * 8)];
            }
#pragma unroll
            for (int f = 0; f < 4; ++f) {
                int n = f * 16 + l16;
                int u0 = (ks * 8 + lq * 2) ^ (n & 15);
                int u1 = (ks * 8 + lq * 2 + 1) ^ (n & 15);
                short4v h0 = *(const short4v*)&Bs[n * 64 + u0 * 4];
                short4v h1 = *(const short4v*)&Bs[n * 64 + u1 * 4];
                b[f] = __builtin_shufflevector(h0, h1, 0, 1, 2, 3, 4, 5, 6, 7);
            }
#pragma unroll
            for (int i = 0; i < 2; ++i)
#pragma unroll
                for (int f = 0; f < 4; ++f)
                    acc[i][f] = __builtin_amdgcn_mfma_f32_16x16x32_bf16(a[i], b[f], acc[i][f], 0, 0, 0);
        }
        __builtin_amdgcn_s_setprio(0);
    }

    int off = offsets[e];
    const float* gbe = gub + (size_t)e * GU_COLS;
#pragma unroll
    for (int j = 0; j < 2; ++j) {
        int col = j * 16 + l16;
        float bg = gbe[nt * 32 + col];
        float bu = gbe[IDIM + nt * 32 + col];
#pragma unroll
        for (int i = 0; i < 2; ++i)
#pragma unroll
            for (int r2 = 0; r2 < 4; ++r2) {
                int row = wave * 32 + i * 16 + lq * 4 + r2;
                int slot = mt * 256 + row;
                if (slot < ne) {
                    float g = acc[i][j][r2] + bg;
                    float u = acc[i][j + 2][r2] + bu;
                    float sg = g / (1.f + expf(-g));
                    inter[(size_t)(off + slot) * IDIM + nt * 32 + col] = f2b(sg * u);
                }
            }
    }
}

// ---------------- Kernel 4: down GEMM -> eo (K-split x2, atomic-free) ------
// NEW vs r12: K split in two halves (0..1472 / 1472..2880) -> 512 live
// blocks = 2/CU (cross-block stage/compute overlap). Each half writes its
// own eo buffer (eo + ksp*ESTRIDE); gather sums both. Bias on ksp==0.
// XCD clustering preserved (xcd = e&7 for both halves).
__global__ __launch_bounds__(512) void down_kernel(
    const unsigned short* __restrict__ inter, const float* __restrict__ dw,
    const float* __restrict__ db, const int* __restrict__ counts,
    const int* __restrict__ offsets, float* __restrict__ eo)
{
    int bid = blockIdx.x;
    int xcd = bid & 7;
    int r   = bid >> 3;          // 0..255
    int ht  = r & 15;
    int s2  = r >> 4;            // 0..15
    int ksp = s2 & 1;
    int s   = s2 >> 1;           // 0..7
    int e   = xcd + ((s & 1) << 3);
    int mt  = s >> 1;            // 0..3
    int ne = counts[e];
    if (mt * 256 >= ne) return;

    int k0   = ksp * 1472;       // 23 / 22 phases
    int kend = ksp ? IDIM : 1472;

    int tid = threadIdx.x;
    int wave = tid >> 6, lane = tid & 63;
    int l16 = lane & 15, lq = lane >> 4;

    __shared__ unsigned short As[256 * 64];   // 32 KB
    __shared__ unsigned short Bs[64 * 64];    // 8 KB

    int off = offsets[e];
    const float* dw_e = dw + (size_t)e * IDIM * HDIM;
    float* eo_k = eo + (size_t)ksp * ESTRIDE;

    int at = tid - 256;
    const unsigned short* asrc[8];
    if (tid >= 256) {
#pragma unroll
        for (int i = 0; i < 8; ++i) {
            int s3 = at + i * 256;
            int row = s3 >> 3, c = s3 & 7;
            int slotr = mt * 256 + row; if (slotr >= ne) slotr = ne - 1;
            asrc[i] = inter + (size_t)(off + slotr) * IDIM + ((c ^ (row & 7)) * 8);
        }
    }
    int nb = tid & 15, kb = tid >> 4;
    const float* bsrc = nullptr;
    if (tid < 256)
        bsrc = dw_e + (size_t)(kb * 4) * HDIM + ht * 64 + nb * 4;

    f32x4 acc[2][4];
#pragma unroll
    for (int i = 0; i < 2; ++i)
#pragma unroll
        for (int f = 0; f < 4; ++f) acc[i][f] = (f32x4){0.f, 0.f, 0.f, 0.f};

    float4 br0, br1, br2, br3;
    if (tid < 256) {
        const float* sp = bsrc + (size_t)k0 * HDIM;
        br0 = *(const float4*)(sp);
        br1 = *(const float4*)(sp + HDIM);
        br2 = *(const float4*)(sp + 2 * HDIM);
        br3 = *(const float4*)(sp + 3 * HDIM);
    }

    for (int kk = k0; kk < kend; kk += 64) {
        __syncthreads();
        if (tid >= 256) {
#pragma unroll
            for (int i = 0; i < 8; ++i)
                gload16(asrc[i] + kk, As + ((size_t)(at + i * 256)) * 8);
        } else {
#pragma unroll
            for (int j = 0; j < 4; ++j) {
                int n = nb * 4 + j;
                int slot = kb ^ (n & 15);
                ushort4v b;
                b.x = f2b((&br0.x)[j]); b.y = f2b((&br1.x)[j]);
                b.z = f2b((&br2.x)[j]); b.w = f2b((&br3.x)[j]);
                *(ushort4v*)&Bs[n * 64 + slot * 4] = b;
            }
        }
        __syncthreads();
        if (tid < 256 && kk + 64 < kend) {
            const float* sp = bsrc + (size_t)(kk + 64) * HDIM;
            br0 = *(const float4*)(sp);
            br1 = *(const float4*)(sp + HDIM);
            br2 = *(const float4*)(sp + 2 * HDIM);
            br3 = *(const float4*)(sp + 3 * HDIM);
        }
        __builtin_amdgcn_s_setprio(1);
#pragma unroll
        for (int ks = 0; ks < 2; ++ks) {
            short8 a[2], b[4];
#pragma unroll
            for (int i = 0; i < 2; ++i) {
                int row = wave * 32 + i * 16 + l16;
                int q = ks * 4 + lq;
                a[i] = *(const short8*)&As[row * 64 + ((q ^ (row & 7)) * 8)];
            }
#pragma unroll
            for (int f = 0; f < 4; ++f) {
                int n = f * 16 + l16;
                int u0 = (ks * 8 + lq * 2) ^ (n & 15);
                int u1 = (ks * 8 + lq * 2 + 1) ^ (n & 15);
                short4v h0 = *(const short4v*)&Bs[n * 64 + u0 * 4];
                short4v h1 = *(const short4v*)&Bs[n * 64 + u1 * 4];
                b[f] = __builtin_shufflevector(h0, h1, 0, 1, 2, 3, 4, 5, 6, 7);
            }
#pragma unroll
            for (int i = 0; i < 2; ++i)
#pragma unroll
                for (int f = 0; f < 4; ++f)
                    acc[i][f] = __builtin_amdgcn_mfma_f32_16x16x32_bf16(a[i], b[f], acc[i][f], 0, 0, 0);
        }
        __builtin_amdgcn_s_setprio(0);
    }

    const float* db_e = db + (size_t)e * HDIM;
#pragma unroll
    for (int f = 0; f < 4; ++f) {
        int h = ht * 64 + f * 16 + l16;
        float bias = (ksp == 0) ? db_e[h] : 0.f;
#pragma unroll
        for (int i = 0; i < 2; ++i)
#pragma unroll
            for (int r2 = 0; r2 < 4; ++r2) {
                int row = wave * 32 + i * 16 + lq * 4 + r2;
                int slot = mt * 256 + row;
                if (slot < ne)
                    eo_k[(size_t)(off + slot) * HDIM + h] = acc[i][f][r2] + bias;
            }
    }
}

// ---------------- Kernel 5: weighted gather (sums both K-halves) -----------
__global__ __launch_bounds__(256) void gather_kernel(
    const float* __restrict__ eo, const int* __restrict__ tokslot4,
    const float* __restrict__ wts4, const int* __restrict__ offsets,
    float* __restrict__ out)
{
    int t = blockIdx.x;
    int tid = threadIdx.x;
    int rows[TOPK]; float w[TOPK];
#pragma unroll
    for (int k = 0; k < TOPK; ++k) {
        int ts = tokslot4[t * TOPK + k];
        int e = ts >> 16, slot = ts & 0xFFFF;
        rows[k] = offsets[e] + slot;
        w[k] = wts4[t * TOPK + k];
    }
    int h0 = tid * 4;
    float4 s = make_float4(0.f, 0.f, 0.f, 0.f);
#pragma unroll
    for (int k = 0; k < TOPK; ++k) {
        float4 v0 = *(const float4*)(eo + (size_t)rows[k] * HDIM + h0);
        float4 v1 = *(const float4*)(eo + ESTRIDE + (size_t)rows[k] * HDIM + h0);
        s.x += w[k] * (v0.x + v1.x); s.y += w[k] * (v0.y + v1.y);
        s.z += w[k] * (v0.z + v1.z); s.w += w[k] * (v0.w + v1.w);
    }
    *(float4*)(out + (size_t)t * HDIM + h0) = s;
}

// ---------------------------------------------------------------------------
extern "C" void kernel_launch(void* const* d_in, const int* in_sizes, int n_in,
                              void* d_out, int out_size, void* d_ws, size_t ws_size,
                              hipStream_t stream)
{
    const float* x   = (const float*)d_in[0];
    const float* gw  = (const float*)d_in[1];
    const float* gb  = (const float*)d_in[2];
    const float* gup = (const float*)d_in[3];
    const float* gub = (const float*)d_in[4];
    const float* dw  = (const float*)d_in[5];
    const float* db  = (const float*)d_in[6];

    float* out        = (float*)d_out;
    float* logits_out = out + (size_t)T_TOK * HDIM;

    char* ws = (char*)d_ws;
    int*   counts   = (int*)(ws + 0);
    int*   offsets  = (int*)(ws + 256);
    int*   lists    = (int*)(ws + 512);                       // 64 KB
    float* wts      = (float*)(ws + 512 + 65536);             // 64 KB
    int*   tokslot4 = (int*)(ws + 512 + 131072);              // 16 KB
    float* wts4     = (float*)(ws + 512 + 131072 + 16384);    // 16 KB
    unsigned short* xb    = (unsigned short*)(ws + 164352);   // 2 MB
    unsigned short* inter = (unsigned short*)(ws + 2261504);  // 23.6 MB
    float*          eo    = (float*)(ws + 25854464);          // 2 x 16.8 MB

    hipMemsetAsync(counts, 0, 64, stream);

    router_kernel<<<T_TOK, 256, 0, stream>>>(x, gw, gb, logits_out, counts, lists, wts, tokslot4, wts4, xb);
    offsets_kernel<<<1, 64, 0, stream>>>(counts, offsets);
    gu_kernel<<<8 * 90 * 8, 512, 0, stream>>>(xb, gup, gub, counts, offsets, lists, inter);
    down_kernel<<<2 * 8 * 16 * 8, 512, 0, stream>>>(inter, dw, db, counts, offsets, eo);
    gather_kernel<<<T_TOK, 256, 0, stream>>>(eo, tokslot4, wts4, offsets, out);
}

// Round 21
// 303.697 us; speedup vs baseline: 1.0555x; 1.0555x over previous
//
#include <hip/hip_runtime.h>
#include <hip/hip_bf16.h>
#include <stdint.h>

#define T_TOK 1024
#define HDIM  1024
#define NEXP  16
#define IDIM  2880
#define GU_COLS (2*IDIM)   // 5760
#define TOPK  4

using short4v  = __attribute__((ext_vector_type(4))) short;
using short8   = __attribute__((ext_vector_type(8))) short;
using ushort4v = __attribute__((ext_vector_type(4))) unsigned short;
using f32x4    = __attribute__((ext_vector_type(4))) float;

__device__ __forceinline__ unsigned short f2b(float f) {
    union { float f; unsigned u; } x; x.f = f;
    unsigned r = x.u + 0x7FFFu + ((x.u >> 16) & 1u);  // RNE
    return (unsigned short)(r >> 16);
}

typedef const __attribute__((address_space(1))) unsigned int* gas1_t;
typedef __attribute__((address_space(3))) unsigned int* las3_t;
__device__ __forceinline__ void gload16(const void* g, void* l) {
    __builtin_amdgcn_global_load_lds((gas1_t)g, (las3_t)l, 16, 0, 0);
}

// ---------------- Kernel 1: router + x->bf16 --------------------------------
__global__ __launch_bounds__(256) void router_kernel(
    const float* __restrict__ x, const float* __restrict__ gw,
    const float* __restrict__ gb, float* __restrict__ logits_out,
    int* __restrict__ counts, int* __restrict__ lists, float* __restrict__ wts,
    int* __restrict__ tokslot4, float* __restrict__ wts4,
    unsigned short* __restrict__ xb)
{
    int t = blockIdx.x;
    int tid = threadIdx.x;
    const float* xr = x + (size_t)t * HDIM;
    {
        float4 v = *(const float4*)(xr + tid * 4);
        ushort4v b; b.x = f2b(v.x); b.y = f2b(v.y); b.z = f2b(v.z); b.w = f2b(v.w);
        *(ushort4v*)(xb + (size_t)t * HDIM + tid * 4) = b;
    }
    int e = tid >> 4;
    int l16 = tid & 15;
    const float* wr = gw + (size_t)e * HDIM;
    float p = 0.f;
    for (int h = l16; h < HDIM; h += 16) p += xr[h] * wr[h];
    p += __shfl_xor(p, 8);
    p += __shfl_xor(p, 4);
    p += __shfl_xor(p, 2);
    p += __shfl_xor(p, 1);
    __shared__ float sl[NEXP];
    if (l16 == 0) {
        float v = p + gb[e];
        sl[e] = v;
        logits_out[t * NEXP + e] = v;
    }
    __syncthreads();
    if (tid == 0) {
        float v[NEXP];
#pragma unroll
        for (int i = 0; i < NEXP; ++i) v[i] = sl[i];
        int idx[TOPK]; float tv[TOPK];
        unsigned used = 0;
#pragma unroll
        for (int k = 0; k < TOPK; ++k) {
            float best = -__builtin_inff(); int bi = 0;
#pragma unroll
            for (int i = 0; i < NEXP; ++i)
                if (!((used >> i) & 1u) && v[i] > best) { best = v[i]; bi = i; }
            used |= 1u << bi; idx[k] = bi; tv[k] = best;
        }
        float m = tv[0];
        float ex[TOPK], s = 0.f;
#pragma unroll
        for (int k = 0; k < TOPK; ++k) { ex[k] = expf(tv[k] - m); s += ex[k]; }
#pragma unroll
        for (int k = 0; k < TOPK; ++k) {
            float w = ex[k] / s;
            int slot = atomicAdd(&counts[idx[k]], 1);
            lists[idx[k] * T_TOK + slot] = t;
            wts[idx[k] * T_TOK + slot] = w;
            tokslot4[t * TOPK + k] = (idx[k] << 16) | slot;
            wts4[t * TOPK + k] = w;
        }
    }
}

// ---------------- Kernel 2: exclusive prefix sum ---------------------------
__global__ void offsets_kernel(const int* __restrict__ counts, int* __restrict__ offsets)
{
    if (threadIdx.x == 0) {
        int o = 0;
        for (int e = 0; e < NEXP; ++e) { offsets[e] = o; o += counts[e]; }
        offsets[NEXP] = o;
    }
}

// ---------------- Kernel 3: gate_up GEMM + silu ----------------------------
// Round-5 structure. XCD-CLUSTERED decode: xcd = e&7, so all 90 nt blocks
// sharing the (e,mt) gathered-A panel land on one XCD -> A reads L2-resident.
__global__ __launch_bounds__(512) void gu_kernel(
    const unsigned short* __restrict__ xb, const float* __restrict__ gup,
    const float* __restrict__ gub, const int* __restrict__ counts,
    const int* __restrict__ offsets, const int* __restrict__ lists,
    unsigned short* __restrict__ inter)
{
    int bid = blockIdx.x;
    int xcd = bid & 7;
    int r   = bid >> 3;          // 0..719
    int nt  = r % 90;
    int s   = r / 90;            // 0..7
    int e   = xcd + ((s & 1) << 3);
    int mt  = s >> 1;            // 0..3
    int ne = counts[e];
    if (mt * 256 >= ne) return;

    int tid = threadIdx.x;
    int wave = tid >> 6, lane = tid & 63;
    int l16 = lane & 15, lq = lane >> 4;

    __shared__ int tokid[256];
    __shared__ unsigned short As[256 * 64];   // 32 KB
    __shared__ unsigned short Bs[64 * 64];    // 8 KB

    if (tid < 256) {
        int slot = mt * 256 + tid;
        tokid[tid] = (slot < ne) ? lists[e * T_TOK + slot] : lists[e * T_TOK];
    }
    __syncthreads();

    const float* gup_e = gup + (size_t)e * HDIM * GU_COLS;

    // A stagers: threads 256..511, 8 x 16B chunks each
    int at = tid - 256;
    const unsigned short* asrc[8];
    if (tid >= 256) {
#pragma unroll
        for (int i = 0; i < 8; ++i) {
            int s2 = at + i * 256;
            int row = s2 >> 3, c = s2 & 7;
            asrc[i] = xb + (size_t)tokid[row] * HDIM + ((c ^ (row & 7)) * 8);
        }
    }
    // B stagers: threads 0..255: nb = n-block(4 cols), kb = k-chunk(4 rows)
    int nb = tid & 15, kb = tid >> 4;
    const float* bsrc = nullptr;
    if (tid < 256) {
        int n0 = nb * 4;
        size_t col = (n0 < 32) ? (size_t)(nt * 32 + n0) : (size_t)(IDIM + nt * 32 + (n0 - 32));
        bsrc = gup_e + (size_t)(kb * 4) * GU_COLS + col;
    }

    f32x4 acc[2][4];
#pragma unroll
    for (int i = 0; i < 2; ++i)
#pragma unroll
        for (int f = 0; f < 4; ++f) acc[i][f] = (f32x4){0.f, 0.f, 0.f, 0.f};

    // B prologue: tile 0 into regs
    float4 br0, br1, br2, br3;
    if (tid < 256) {
        br0 = *(const float4*)(bsrc);
        br1 = *(const float4*)(bsrc + GU_COLS);
        br2 = *(const float4*)(bsrc + 2 * GU_COLS);
        br3 = *(const float4*)(bsrc + 3 * GU_COLS);
    }

    for (int kk = 0; kk < HDIM; kk += 64) {
        __syncthreads();                       // LDS free (prev readers done)
        if (tid >= 256) {
#pragma unroll
            for (int i = 0; i < 8; ++i)
                gload16(asrc[i] + kk, As + ((size_t)(at + i * 256)) * 8);
        } else {
            // convert + write B tile kk from regs
#pragma unroll
            for (int j = 0; j < 4; ++j) {
                int n = nb * 4 + j;
                int slot = kb ^ (n & 15);
                ushort4v b;
                b.x = f2b((&br0.x)[j]); b.y = f2b((&br1.x)[j]);
                b.z = f2b((&br2.x)[j]); b.w = f2b((&br3.x)[j]);
                *(ushort4v*)&Bs[n * 64 + slot * 4] = b;
            }
        }
        __syncthreads();                       // drains vmcnt (A) + lgkm (B)
        // T14: issue B loads for tile kk+64 — in flight during MFMA below
        if (tid < 256 && kk + 64 < HDIM) {
            const float* sp = bsrc + (size_t)(kk + 64) * GU_COLS;
            br0 = *(const float4*)(sp);
            br1 = *(const float4*)(sp + GU_COLS);
            br2 = *(const float4*)(sp + 2 * GU_COLS);
            br3 = *(const float4*)(sp + 3 * GU_COLS);
        }
        __builtin_amdgcn_s_setprio(1);
#pragma unroll
        for (int ks = 0; ks < 2; ++ks) {
            short8 a[2], b[4];
#pragma unroll
            for (int i = 0; i < 2; ++i) {
                int row = wave * 32 + i * 16 + l16;
                int q = ks * 4 + lq;
                a[i] = *(const short8*)&As[row * 64 + ((q ^ (row & 7)) * 8)];
            }
#pragma unroll
            for (int f = 0; f < 4; ++f) {
                int n = f * 16 + l16;
                int u0 = (ks * 8 + lq * 2) ^ (n & 15);
                int u1 = (ks * 8 + lq * 2 + 1) ^ (n & 15);
                short4v h0 = *(const short4v*)&Bs[n * 64 + u0 * 4];
                short4v h1 = *(const short4v*)&Bs[n * 64 + u1 * 4];
                b[f] = __builtin_shufflevector(h0, h1, 0, 1, 2, 3, 4, 5, 6, 7);
            }
#pragma unroll
            for (int i = 0; i < 2; ++i)
#pragma unroll
                for (int f = 0; f < 4; ++f)
                    acc[i][f] = __builtin_amdgcn_mfma_f32_16x16x32_bf16(a[i], b[f], acc[i][f], 0, 0, 0);
        }
        __builtin_amdgcn_s_setprio(0);
    }

    // ---- epilogue: intra-wave silu(gate)*up ----
    int off = offsets[e];
    const float* gbe = gub + (size_t)e * GU_COLS;
#pragma unroll
    for (int j = 0; j < 2; ++j) {
        int col = j * 16 + l16;
        float bg = gbe[nt * 32 + col];
        float bu = gbe[IDIM + nt * 32 + col];
#pragma unroll
        for (int i = 0; i < 2; ++i)
#pragma unroll
            for (int r2 = 0; r2 < 4; ++r2) {
                int row = wave * 32 + i * 16 + lq * 4 + r2;
                int slot = mt * 256 + row;
                if (slot < ne) {
                    float g = acc[i][j][r2] + bg;
                    float u = acc[i][j + 2][r2] + bu;
                    float sg = g / (1.f + expf(-g));
                    inter[(size_t)(off + slot) * IDIM + nt * 32 + col] = f2b(sg * u);
                }
            }
    }
}

// ---------------- Kernel 4: down GEMM -> eo (atomic-free) ------------------
// XCD-CLUSTERED decode: xcd = e&7, so all 16 ht blocks sharing the (e,mt)
// inter panel (1.5 MB) land on one XCD -> inter re-reads L2-resident.
__global__ __launch_bounds__(512) void down_kernel(
    const unsigned short* __restrict__ inter, const float* __restrict__ dw,
    const float* __restrict__ db, const int* __restrict__ counts,
    const int* __restrict__ offsets, float* __restrict__ eo)
{
    int bid = blockIdx.x;
    int xcd = bid & 7;
    int r   = bid >> 3;          // 0..127
    int ht  = r & 15;
    int s   = r >> 4;            // 0..7
    int e   = xcd + ((s & 1) << 3);
    int mt  = s >> 1;            // 0..3
    int ne = counts[e];
    if (mt * 256 >= ne) return;

    int tid = threadIdx.x;
    int wave = tid >> 6, lane = tid & 63;
    int l16 = lane & 15, lq = lane >> 4;

    __shared__ unsigned short As[256 * 64];   // 32 KB
    __shared__ unsigned short Bs[64 * 64];    // 8 KB

    int off = offsets[e];

    const float* dw_e = dw + (size_t)e * IDIM * HDIM;

    int at = tid - 256;
    const unsigned short* asrc[8];
    if (tid >= 256) {
#pragma unroll
        for (int i = 0; i < 8; ++i) {
            int s2 = at + i * 256;
            int row = s2 >> 3, c = s2 & 7;
            int slotr = mt * 256 + row; if (slotr >= ne) slotr = ne - 1;
            asrc[i] = inter + (size_t)(off + slotr) * IDIM + ((c ^ (row & 7)) * 8);
        }
    }
    int nb = tid & 15, kb = tid >> 4;
    const float* bsrc = nullptr;
    if (tid < 256)
        bsrc = dw_e + (size_t)(kb * 4) * HDIM + ht * 64 + nb * 4;

    f32x4 acc[2][4];
#pragma unroll
    for (int i = 0; i < 2; ++i)
#pragma unroll
        for (int f = 0; f < 4; ++f) acc[i][f] = (f32x4){0.f, 0.f, 0.f, 0.f};

    float4 br0, br1, br2, br3;
    if (tid < 256) {
        br0 = *(const float4*)(bsrc);
        br1 = *(const float4*)(bsrc + HDIM);
        br2 = *(const float4*)(bsrc + 2 * HDIM);
        br3 = *(const float4*)(bsrc + 3 * HDIM);
    }

    for (int kk = 0; kk < IDIM; kk += 64) {
        __syncthreads();
        if (tid >= 256) {
#pragma unroll
            for (int i = 0; i < 8; ++i)
                gload16(asrc[i] + kk, As + ((size_t)(at + i * 256)) * 8);
        } else {
#pragma unroll
            for (int j = 0; j < 4; ++j) {
                int n = nb * 4 + j;
                int slot = kb ^ (n & 15);
                ushort4v b;
                b.x = f2b((&br0.x)[j]); b.y = f2b((&br1.x)[j]);
                b.z = f2b((&br2.x)[j]); b.w = f2b((&br3.x)[j]);
                *(ushort4v*)&Bs[n * 64 + slot * 4] = b;
            }
        }
        __syncthreads();
        if (tid < 256 && kk + 64 < IDIM) {
            const float* sp = bsrc + (size_t)(kk + 64) * HDIM;
            br0 = *(const float4*)(sp);
            br1 = *(const float4*)(sp + HDIM);
            br2 = *(const float4*)(sp + 2 * HDIM);
            br3 = *(const float4*)(sp + 3 * HDIM);
        }
        __builtin_amdgcn_s_setprio(1);
#pragma unroll
        for (int ks = 0; ks < 2; ++ks) {
            short8 a[2], b[4];
#pragma unroll
            for (int i = 0; i < 2; ++i) {
                int row = wave * 32 + i * 16 + l16;
                int q = ks * 4 + lq;
                a[i] = *(const short8*)&As[row * 64 + ((q ^ (row & 7)) * 8)];
            }
#pragma unroll
            for (int f = 0; f < 4; ++f) {
                int n = f * 16 + l16;
                int u0 = (ks * 8 + lq * 2) ^ (n & 15);
                int u1 = (ks * 8 + lq * 2 + 1) ^ (n & 15);
                short4v h0 = *(const short4v*)&Bs[n * 64 + u0 * 4];
                short4v h1 = *(const short4v*)&Bs[n * 64 + u1 * 4];
                b[f] = __builtin_shufflevector(h0, h1, 0, 1, 2, 3, 4, 5, 6, 7);
            }
#pragma unroll
            for (int i = 0; i < 2; ++i)
#pragma unroll
                for (int f = 0; f < 4; ++f)
                    acc[i][f] = __builtin_amdgcn_mfma_f32_16x16x32_bf16(a[i], b[f], acc[i][f], 0, 0, 0);
        }
        __builtin_amdgcn_s_setprio(0);
    }

    const float* db_e = db + (size_t)e * HDIM;
#pragma unroll
    for (int f = 0; f < 4; ++f) {
        int h = ht * 64 + f * 16 + l16;
        float bias = db_e[h];
#pragma unroll
        for (int i = 0; i < 2; ++i)
#pragma unroll
            for (int r2 = 0; r2 < 4; ++r2) {
                int row = wave * 32 + i * 16 + lq * 4 + r2;
                int slot = mt * 256 + row;
                if (slot < ne)
                    eo[(size_t)(off + slot) * HDIM + h] = acc[i][f][r2] + bias;
            }
    }
}

// ---------------- Kernel 5: weighted gather --------------------------------
__global__ __launch_bounds__(256) void gather_kernel(
    const float* __restrict__ eo, const int* __restrict__ tokslot4,
    const float* __restrict__ wts4, const int* __restrict__ offsets,
    float* __restrict__ out)
{
    int t = blockIdx.x;
    int tid = threadIdx.x;
    int rows[TOPK]; float w[TOPK];
#pragma unroll
    for (int k = 0; k < TOPK; ++k) {
        int ts = tokslot4[t * TOPK + k];
        int e = ts >> 16, slot = ts & 0xFFFF;
        rows[k] = offsets[e] + slot;
        w[k] = wts4[t * TOPK + k];
    }
    int h0 = tid * 4;
    float4 s = make_float4(0.f, 0.f, 0.f, 0.f);
#pragma unroll
    for (int k = 0; k < TOPK; ++k) {
        float4 v = *(const float4*)(eo + (size_t)rows[k] * HDIM + h0);
        s.x += w[k] * v.x; s.y += w[k] * v.y;
        s.z += w[k] * v.z; s.w += w[k] * v.w;
    }
    *(float4*)(out + (size_t)t * HDIM + h0) = s;
}

// ---------------------------------------------------------------------------
extern "C" void kernel_launch(void* const* d_in, const int* in_sizes, int n_in,
                              void* d_out, int out_size, void* d_ws, size_t ws_size,
                              hipStream_t stream)
{
    const float* x   = (const float*)d_in[0];
    const float* gw  = (const float*)d_in[1];
    const float* gb  = (const float*)d_in[2];
    const float* gup = (const float*)d_in[3];
    const float* gub = (const float*)d_in[4];
    const float* dw  = (const float*)d_in[5];
    const float* db  = (const float*)d_in[6];

    float* out        = (float*)d_out;
    float* logits_out = out + (size_t)T_TOK * HDIM;

    char* ws = (char*)d_ws;
    int*   counts   = (int*)(ws + 0);
    int*   offsets  = (int*)(ws + 256);
    int*   lists    = (int*)(ws + 512);                       // 64 KB
    float* wts      = (float*)(ws + 512 + 65536);             // 64 KB
    int*   tokslot4 = (int*)(ws + 512 + 131072);              // 16 KB
    float* wts4     = (float*)(ws + 512 + 131072 + 16384);    // 16 KB
    unsigned short* xb    = (unsigned short*)(ws + 164352);   // 2 MB
    unsigned short* inter = (unsigned short*)(ws + 2261504);  // 23.6 MB
    float*          eo    = (float*)(ws + 25854464);          // 16.8 MB

    hipMemsetAsync(counts, 0, 64, stream);

    router_kernel<<<T_TOK, 256, 0, stream>>>(x, gw, gb, logits_out, counts, lists, wts, tokslot4, wts4, xb);
    offsets_kernel<<<1, 64, 0, stream>>>(counts, offsets);
    gu_kernel<<<8 * 90 * 8, 512, 0, stream>>>(xb, gup, gub, counts, offsets, lists, inter);
    down_kernel<<<8 * 16 * 8, 512, 0, stream>>>(inter, dw, db, counts, offsets, eo);
    gather_kernel<<<T_TOK, 256, 0, stream>>>(eo, tokslot4, wts4, offsets, out);
}

// Round 22
// 302.898 us; speedup vs baseline: 1.0583x; 1.0026x over previous
//
#include <hip/hip_runtime.h>
#include <hip/hip_bf16.h>
#include <stdint.h>

#define T_TOK 1024
#define HDIM  1024
#define NEXP  16
#define IDIM  2880
#define GU_COLS (2*IDIM)   // 5760
#define TOPK  4

using short4v  = __attribute__((ext_vector_type(4))) short;
using short8   = __attribute__((ext_vector_type(8))) short;
using ushort4v = __attribute__((ext_vector_type(4))) unsigned short;
using f32x4    = __attribute__((ext_vector_type(4))) float;

__device__ __forceinline__ unsigned short f2b(float f) {
    union { float f; unsigned u; } x; x.f = f;
    unsigned r = x.u + 0x7FFFu + ((x.u >> 16) & 1u);  // RNE
    return (unsigned short)(r >> 16);
}

typedef const __attribute__((address_space(1))) unsigned int* gas1_t;
typedef __attribute__((address_space(3))) unsigned int* las3_t;
__device__ __forceinline__ void gload16(const void* g, void* l) {
    __builtin_amdgcn_global_load_lds((gas1_t)g, (las3_t)l, 16, 0, 0);
}

// in-kernel exclusive prefix over counts[0..NEXP) up to e (counts final
// after router's kernel boundary; 16 L1-hot scalar loads, unrolled)
__device__ __forceinline__ int prefix_off(const int* __restrict__ counts, int e) {
    int o = 0;
#pragma unroll
    for (int i = 0; i < NEXP; ++i)
        if (i < e) o += counts[i];
    return o;
}

// ---------------- Kernel 1: router + x->bf16 --------------------------------
__global__ __launch_bounds__(256) void router_kernel(
    const float* __restrict__ x, const float* __restrict__ gw,
    const float* __restrict__ gb, float* __restrict__ logits_out,
    int* __restrict__ counts, int* __restrict__ lists, float* __restrict__ wts,
    int* __restrict__ tokslot4, float* __restrict__ wts4,
    unsigned short* __restrict__ xb)
{
    int t = blockIdx.x;
    int tid = threadIdx.x;
    const float* xr = x + (size_t)t * HDIM;
    {
        float4 v = *(const float4*)(xr + tid * 4);
        ushort4v b; b.x = f2b(v.x); b.y = f2b(v.y); b.z = f2b(v.z); b.w = f2b(v.w);
        *(ushort4v*)(xb + (size_t)t * HDIM + tid * 4) = b;
    }
    int e = tid >> 4;
    int l16 = tid & 15;
    const float* wr = gw + (size_t)e * HDIM;
    float p = 0.f;
    for (int h = l16; h < HDIM; h += 16) p += xr[h] * wr[h];
    p += __shfl_xor(p, 8);
    p += __shfl_xor(p, 4);
    p += __shfl_xor(p, 2);
    p += __shfl_xor(p, 1);
    __shared__ float sl[NEXP];
    if (l16 == 0) {
        float v = p + gb[e];
        sl[e] = v;
        logits_out[t * NEXP + e] = v;
    }
    __syncthreads();
    if (tid == 0) {
        float v[NEXP];
#pragma unroll
        for (int i = 0; i < NEXP; ++i) v[i] = sl[i];
        int idx[TOPK]; float tv[TOPK];
        unsigned used = 0;
#pragma unroll
        for (int k = 0; k < TOPK; ++k) {
            float best = -__builtin_inff(); int bi = 0;
#pragma unroll
            for (int i = 0; i < NEXP; ++i)
                if (!((used >> i) & 1u) && v[i] > best) { best = v[i]; bi = i; }
            used |= 1u << bi; idx[k] = bi; tv[k] = best;
        }
        float m = tv[0];
        float ex[TOPK], s = 0.f;
#pragma unroll
        for (int k = 0; k < TOPK; ++k) { ex[k] = expf(tv[k] - m); s += ex[k]; }
#pragma unroll
        for (int k = 0; k < TOPK; ++k) {
            float w = ex[k] / s;
            int slot = atomicAdd(&counts[idx[k]], 1);
            lists[idx[k] * T_TOK + slot] = t;
            wts[idx[k] * T_TOK + slot] = w;
            tokslot4[t * TOPK + k] = (idx[k] << 16) | slot;
            wts4[t * TOPK + k] = w;
        }
    }
}

// ---------------- Kernel 3: gate_up GEMM + silu ----------------------------
// Round-12 best structure; offsets computed in-kernel (offsets launch dropped).
__global__ __launch_bounds__(512) void gu_kernel(
    const unsigned short* __restrict__ xb, const float* __restrict__ gup,
    const float* __restrict__ gub, const int* __restrict__ counts,
    const int* __restrict__ lists, unsigned short* __restrict__ inter)
{
    int bid = blockIdx.x;
    int xcd = bid & 7;
    int r   = bid >> 3;          // 0..719
    int nt  = r % 90;
    int s   = r / 90;            // 0..7
    int e   = xcd + ((s & 1) << 3);
    int mt  = s >> 1;            // 0..3
    int ne = counts[e];
    if (mt * 256 >= ne) return;

    int tid = threadIdx.x;
    int wave = tid >> 6, lane = tid & 63;
    int l16 = lane & 15, lq = lane >> 4;

    __shared__ int tokid[256];
    __shared__ unsigned short As[256 * 64];   // 32 KB
    __shared__ unsigned short Bs[64 * 64];    // 8 KB

    if (tid < 256) {
        int slot = mt * 256 + tid;
        tokid[tid] = (slot < ne) ? lists[e * T_TOK + slot] : lists[e * T_TOK];
    }
    __syncthreads();

    const float* gup_e = gup + (size_t)e * HDIM * GU_COLS;

    // A stagers: threads 256..511, 8 x 16B chunks each
    int at = tid - 256;
    const unsigned short* asrc[8];
    if (tid >= 256) {
#pragma unroll
        for (int i = 0; i < 8; ++i) {
            int s2 = at + i * 256;
            int row = s2 >> 3, c = s2 & 7;
            asrc[i] = xb + (size_t)tokid[row] * HDIM + ((c ^ (row & 7)) * 8);
        }
    }
    // B stagers: threads 0..255: nb = n-block(4 cols), kb = k-chunk(4 rows)
    int nb = tid & 15, kb = tid >> 4;
    const float* bsrc = nullptr;
    if (tid < 256) {
        int n0 = nb * 4;
        size_t col = (n0 < 32) ? (size_t)(nt * 32 + n0) : (size_t)(IDIM + nt * 32 + (n0 - 32));
        bsrc = gup_e + (size_t)(kb * 4) * GU_COLS + col;
    }

    f32x4 acc[2][4];
#pragma unroll
    for (int i = 0; i < 2; ++i)
#pragma unroll
        for (int f = 0; f < 4; ++f) acc[i][f] = (f32x4){0.f, 0.f, 0.f, 0.f};

    // B prologue: tile 0 into regs
    float4 br0, br1, br2, br3;
    if (tid < 256) {
        br0 = *(const float4*)(bsrc);
        br1 = *(const float4*)(bsrc + GU_COLS);
        br2 = *(const float4*)(bsrc + 2 * GU_COLS);
        br3 = *(const float4*)(bsrc + 3 * GU_COLS);
    }

    for (int kk = 0; kk < HDIM; kk += 64) {
        __syncthreads();                       // LDS free (prev readers done)
        if (tid >= 256) {
#pragma unroll
            for (int i = 0; i < 8; ++i)
                gload16(asrc[i] + kk, As + ((size_t)(at + i * 256)) * 8);
        } else {
            // convert + write B tile kk from regs
#pragma unroll
            for (int j = 0; j < 4; ++j) {
                int n = nb * 4 + j;
                int slot = kb ^ (n & 15);
                ushort4v b;
                b.x = f2b((&br0.x)[j]); b.y = f2b((&br1.x)[j]);
                b.z = f2b((&br2.x)[j]); b.w = f2b((&br3.x)[j]);
                *(ushort4v*)&Bs[n * 64 + slot * 4] = b;
            }
        }
        __syncthreads();                       // drains vmcnt (A) + lgkm (B)
        // T14: issue B loads for tile kk+64 — in flight during MFMA below
        if (tid < 256 && kk + 64 < HDIM) {
            const float* sp = bsrc + (size_t)(kk + 64) * GU_COLS;
            br0 = *(const float4*)(sp);
            br1 = *(const float4*)(sp + GU_COLS);
            br2 = *(const float4*)(sp + 2 * GU_COLS);
            br3 = *(const float4*)(sp + 3 * GU_COLS);
        }
        __builtin_amdgcn_s_setprio(1);
#pragma unroll
        for (int ks = 0; ks < 2; ++ks) {
            short8 a[2], b[4];
#pragma unroll
            for (int i = 0; i < 2; ++i) {
                int row = wave * 32 + i * 16 + l16;
                int q = ks * 4 + lq;
                a[i] = *(const short8*)&As[row * 64 + ((q ^ (row & 7)) * 8)];
            }
#pragma unroll
            for (int f = 0; f < 4; ++f) {
                int n = f * 16 + l16;
                int u0 = (ks * 8 + lq * 2) ^ (n & 15);
                int u1 = (ks * 8 + lq * 2 + 1) ^ (n & 15);
                short4v h0 = *(const short4v*)&Bs[n * 64 + u0 * 4];
                short4v h1 = *(const short4v*)&Bs[n * 64 + u1 * 4];
                b[f] = __builtin_shufflevector(h0, h1, 0, 1, 2, 3, 4, 5, 6, 7);
            }
#pragma unroll
            for (int i = 0; i < 2; ++i)
#pragma unroll
                for (int f = 0; f < 4; ++f)
                    acc[i][f] = __builtin_amdgcn_mfma_f32_16x16x32_bf16(a[i], b[f], acc[i][f], 0, 0, 0);
        }
        __builtin_amdgcn_s_setprio(0);
    }

    // ---- epilogue: intra-wave silu(gate)*up ----
    int off = prefix_off(counts, e);
    const float* gbe = gub + (size_t)e * GU_COLS;
#pragma unroll
    for (int j = 0; j < 2; ++j) {
        int col = j * 16 + l16;
        float bg = gbe[nt * 32 + col];
        float bu = gbe[IDIM + nt * 32 + col];
#pragma unroll
        for (int i = 0; i < 2; ++i)
#pragma unroll
            for (int r2 = 0; r2 < 4; ++r2) {
                int row = wave * 32 + i * 16 + lq * 4 + r2;
                int slot = mt * 256 + row;
                if (slot < ne) {
                    float g = acc[i][j][r2] + bg;
                    float u = acc[i][j + 2][r2] + bu;
                    float sg = g / (1.f + expf(-g));
                    inter[(size_t)(off + slot) * IDIM + nt * 32 + col] = f2b(sg * u);
                }
            }
    }
}

// ---------------- Kernel 4: down GEMM -> eo (atomic-free) ------------------
__global__ __launch_bounds__(512) void down_kernel(
    const unsigned short* __restrict__ inter, const float* __restrict__ dw,
    const float* __restrict__ db, const int* __restrict__ counts,
    float* __restrict__ eo)
{
    int bid = blockIdx.x;
    int xcd = bid & 7;
    int r   = bid >> 3;          // 0..127
    int ht  = r & 15;
    int s   = r >> 4;            // 0..7
    int e   = xcd + ((s & 1) << 3);
    int mt  = s >> 1;            // 0..3
    int ne = counts[e];
    if (mt * 256 >= ne) return;

    int tid = threadIdx.x;
    int wave = tid >> 6, lane = tid & 63;
    int l16 = lane & 15, lq = lane >> 4;

    __shared__ unsigned short As[256 * 64];   // 32 KB
    __shared__ unsigned short Bs[64 * 64];    // 8 KB

    int off = prefix_off(counts, e);

    const float* dw_e = dw + (size_t)e * IDIM * HDIM;

    int at = tid - 256;
    const unsigned short* asrc[8];
    if (tid >= 256) {
#pragma unroll
        for (int i = 0; i < 8; ++i) {
            int s2 = at + i * 256;
            int row = s2 >> 3, c = s2 & 7;
            int slotr = mt * 256 + row; if (slotr >= ne) slotr = ne - 1;
            asrc[i] = inter + (size_t)(off + slotr) * IDIM + ((c ^ (row & 7)) * 8);
        }
    }
    int nb = tid & 15, kb = tid >> 4;
    const float* bsrc = nullptr;
    if (tid < 256)
        bsrc = dw_e + (size_t)(kb * 4) * HDIM + ht * 64 + nb * 4;

    f32x4 acc[2][4];
#pragma unroll
    for (int i = 0; i < 2; ++i)
#pragma unroll
        for (int f = 0; f < 4; ++f) acc[i][f] = (f32x4){0.f, 0.f, 0.f, 0.f};

    float4 br0, br1, br2, br3;
    if (tid < 256) {
        br0 = *(const float4*)(bsrc);
        br1 = *(const float4*)(bsrc + HDIM);
        br2 = *(const float4*)(bsrc + 2 * HDIM);
        br3 = *(const float4*)(bsrc + 3 * HDIM);
    }

    for (int kk = 0; kk < IDIM; kk += 64) {
        __syncthreads();
        if (tid >= 256) {
#pragma unroll
            for (int i = 0; i < 8; ++i)
                gload16(asrc[i] + kk, As + ((size_t)(at + i * 256)) * 8);
        } else {
#pragma unroll
            for (int j = 0; j < 4; ++j) {
                int n = nb * 4 + j;
                int slot = kb ^ (n & 15);
                ushort4v b;
                b.x = f2b((&br0.x)[j]); b.y = f2b((&br1.x)[j]);
                b.z = f2b((&br2.x)[j]); b.w = f2b((&br3.x)[j]);
                *(ushort4v*)&Bs[n * 64 + slot * 4] = b;
            }
        }
        __syncthreads();
        if (tid < 256 && kk + 64 < IDIM) {
            const float* sp = bsrc + (size_t)(kk + 64) * HDIM;
            br0 = *(const float4*)(sp);
            br1 = *(const float4*)(sp + HDIM);
            br2 = *(const float4*)(sp + 2 * HDIM);
            br3 = *(const float4*)(sp + 3 * HDIM);
        }
        __builtin_amdgcn_s_setprio(1);
#pragma unroll
        for (int ks = 0; ks < 2; ++ks) {
            short8 a[2], b[4];
#pragma unroll
            for (int i = 0; i < 2; ++i) {
                int row = wave * 32 + i * 16 + l16;
                int q = ks * 4 + lq;
                a[i] = *(const short8*)&As[row * 64 + ((q ^ (row & 7)) * 8)];
            }
#pragma unroll
            for (int f = 0; f < 4; ++f) {
                int n = f * 16 + l16;
                int u0 = (ks * 8 + lq * 2) ^ (n & 15);
                int u1 = (ks * 8 + lq * 2 + 1) ^ (n & 15);
                short4v h0 = *(const short4v*)&Bs[n * 64 + u0 * 4];
                short4v h1 = *(const short4v*)&Bs[n * 64 + u1 * 4];
                b[f] = __builtin_shufflevector(h0, h1, 0, 1, 2, 3, 4, 5, 6, 7);
            }
#pragma unroll
            for (int i = 0; i < 2; ++i)
#pragma unroll
                for (int f = 0; f < 4; ++f)
                    acc[i][f] = __builtin_amdgcn_mfma_f32_16x16x32_bf16(a[i], b[f], acc[i][f], 0, 0, 0);
        }
        __builtin_amdgcn_s_setprio(0);
    }

    const float* db_e = db + (size_t)e * HDIM;
#pragma unroll
    for (int f = 0; f < 4; ++f) {
        int h = ht * 64 + f * 16 + l16;
        float bias = db_e[h];
#pragma unroll
        for (int i = 0; i < 2; ++i)
#pragma unroll
            for (int r2 = 0; r2 < 4; ++r2) {
                int row = wave * 32 + i * 16 + lq * 4 + r2;
                int slot = mt * 256 + row;
                if (slot < ne)
                    eo[(size_t)(off + slot) * HDIM + h] = acc[i][f][r2] + bias;
            }
    }
}

// ---------------- Kernel 5: weighted gather --------------------------------
__global__ __launch_bounds__(256) void gather_kernel(
    const float* __restrict__ eo, const int* __restrict__ tokslot4,
    const float* __restrict__ wts4, const int* __restrict__ counts,
    float* __restrict__ out)
{
    int t = blockIdx.x;
    int tid = threadIdx.x;
    // per-thread exclusive prefix of counts (L1-hot, 16 loads)
    int offs[NEXP];
    {
        int o = 0;
#pragma unroll
        for (int i = 0; i < NEXP; ++i) { offs[i] = o; o += counts[i]; }
    }
    int rows[TOPK]; float w[TOPK];
#pragma unroll
    for (int k = 0; k < TOPK; ++k) {
        int ts = tokslot4[t * TOPK + k];
        int e = ts >> 16, slot = ts & 0xFFFF;
        rows[k] = offs[e] + slot;
        w[k] = wts4[t * TOPK + k];
    }
    int h0 = tid * 4;
    float4 s = make_float4(0.f, 0.f, 0.f, 0.f);
#pragma unroll
    for (int k = 0; k < TOPK; ++k) {
        float4 v = *(const float4*)(eo + (size_t)rows[k] * HDIM + h0);
        s.x += w[k] * v.x; s.y += w[k] * v.y;
        s.z += w[k] * v.z; s.w += w[k] * v.w;
    }
    *(float4*)(out + (size_t)t * HDIM + h0) = s;
}

// ---------------------------------------------------------------------------
extern "C" void kernel_launch(void* const* d_in, const int* in_sizes, int n_in,
                              void* d_out, int out_size, void* d_ws, size_t ws_size,
                              hipStream_t stream)
{
    const float* x   = (const float*)d_in[0];
    const float* gw  = (const float*)d_in[1];
    const float* gb  = (const float*)d_in[2];
    const float* gup = (const float*)d_in[3];
    const float* gub = (const float*)d_in[4];
    const float* dw  = (const float*)d_in[5];
    const float* db  = (const float*)d_in[6];

    float* out        = (float*)d_out;
    float* logits_out = out + (size_t)T_TOK * HDIM;

    char* ws = (char*)d_ws;
    int*   counts   = (int*)(ws + 0);
    int*   lists    = (int*)(ws + 512);                       // 64 KB
    float* wts      = (float*)(ws + 512 + 65536);             // 64 KB
    int*   tokslot4 = (int*)(ws + 512 + 131072);              // 16 KB
    float* wts4     = (float*)(ws + 512 + 131072 + 16384);    // 16 KB
    unsigned short* xb    = (unsigned short*)(ws + 164352);   // 2 MB
    unsigned short* inter = (unsigned short*)(ws + 2261504);  // 23.6 MB
    float*          eo    = (float*)(ws + 25854464);          // 16.8 MB

    hipMemsetAsync(counts, 0, 64, stream);

    router_kernel<<<T_TOK, 256, 0, stream>>>(x, gw, gb, logits_out, counts, lists, wts, tokslot4, wts4, xb);
    gu_kernel<<<8 * 90 * 8, 512, 0, stream>>>(xb, gup, gub, counts, lists, inter);
    down_kernel<<<8 * 16 * 8, 512, 0, stream>>>(inter, dw, db, counts, eo);
    gather_kernel<<<T_TOK, 256, 0, stream>>>(eo, tokslot4, wts4, counts, out);
}

// Round 23
// 300.620 us; speedup vs baseline: 1.0663x; 1.0076x over previous
//
#include <hip/hip_runtime.h>
#include <hip/hip_bf16.h>
#include <stdint.h>

#define T_TOK 1024
#define HDIM  1024
#define NEXP  16
#define IDIM  2880
#define GU_COLS (2*IDIM)   // 5760
#define TOPK  4

using short4v  = __attribute__((ext_vector_type(4))) short;
using short8   = __attribute__((ext_vector_type(8))) short;
using ushort4v = __attribute__((ext_vector_type(4))) unsigned short;
using f32x4    = __attribute__((ext_vector_type(4))) float;

__device__ __forceinline__ unsigned short f2b(float f) {
    union { float f; unsigned u; } x; x.f = f;
    unsigned r = x.u + 0x7FFFu + ((x.u >> 16) & 1u);  // RNE
    return (unsigned short)(r >> 16);
}
__device__ __forceinline__ float b2f(unsigned short b) {
    union { unsigned u; float f; } x; x.u = ((unsigned)b) << 16;
    return x.f;
}

typedef const __attribute__((address_space(1))) unsigned int* gas1_t;
typedef __attribute__((address_space(3))) unsigned int* las3_t;
__device__ __forceinline__ void gload16(const void* g, void* l) {
    __builtin_amdgcn_global_load_lds((gas1_t)g, (las3_t)l, 16, 0, 0);
}

// in-kernel exclusive prefix over counts[0..NEXP) up to e
__device__ __forceinline__ int prefix_off(const int* __restrict__ counts, int e) {
    int o = 0;
#pragma unroll
    for (int i = 0; i < NEXP; ++i)
        if (i < e) o += counts[i];
    return o;
}

// ---------------- Kernel 1: router + x->bf16 --------------------------------
__global__ __launch_bounds__(256) void router_kernel(
    const float* __restrict__ x, const float* __restrict__ gw,
    const float* __restrict__ gb, float* __restrict__ logits_out,
    int* __restrict__ counts, int* __restrict__ lists, float* __restrict__ wts,
    int* __restrict__ tokslot4, float* __restrict__ wts4,
    unsigned short* __restrict__ xb)
{
    int t = blockIdx.x;
    int tid = threadIdx.x;
    const float* xr = x + (size_t)t * HDIM;
    {
        float4 v = *(const float4*)(xr + tid * 4);
        ushort4v b; b.x = f2b(v.x); b.y = f2b(v.y); b.z = f2b(v.z); b.w = f2b(v.w);
        *(ushort4v*)(xb + (size_t)t * HDIM + tid * 4) = b;
    }
    int e = tid >> 4;
    int l16 = tid & 15;
    const float* wr = gw + (size_t)e * HDIM;
    float p = 0.f;
    for (int h = l16; h < HDIM; h += 16) p += xr[h] * wr[h];
    p += __shfl_xor(p, 8);
    p += __shfl_xor(p, 4);
    p += __shfl_xor(p, 2);
    p += __shfl_xor(p, 1);
    __shared__ float sl[NEXP];
    if (l16 == 0) {
        float v = p + gb[e];
        sl[e] = v;
        logits_out[t * NEXP + e] = v;
    }
    __syncthreads();
    if (tid == 0) {
        float v[NEXP];
#pragma unroll
        for (int i = 0; i < NEXP; ++i) v[i] = sl[i];
        int idx[TOPK]; float tv[TOPK];
        unsigned used = 0;
#pragma unroll
        for (int k = 0; k < TOPK; ++k) {
            float best = -__builtin_inff(); int bi = 0;
#pragma unroll
            for (int i = 0; i < NEXP; ++i)
                if (!((used >> i) & 1u) && v[i] > best) { best = v[i]; bi = i; }
            used |= 1u << bi; idx[k] = bi; tv[k] = best;
        }
        float m = tv[0];
        float ex[TOPK], s = 0.f;
#pragma unroll
        for (int k = 0; k < TOPK; ++k) { ex[k] = expf(tv[k] - m); s += ex[k]; }
#pragma unroll
        for (int k = 0; k < TOPK; ++k) {
            float w = ex[k] / s;
            int slot = atomicAdd(&counts[idx[k]], 1);
            lists[idx[k] * T_TOK + slot] = t;
            wts[idx[k] * T_TOK + slot] = w;
            tokslot4[t * TOPK + k] = (idx[k] << 16) | slot;
            wts4[t * TOPK + k] = w;
        }
    }
}

// ---------------- Kernel 3: gate_up GEMM + silu ----------------------------
__global__ __launch_bounds__(512) void gu_kernel(
    const unsigned short* __restrict__ xb, const float* __restrict__ gup,
    const float* __restrict__ gub, const int* __restrict__ counts,
    const int* __restrict__ lists, unsigned short* __restrict__ inter)
{
    int bid = blockIdx.x;
    int xcd = bid & 7;
    int r   = bid >> 3;          // 0..719
    int nt  = r % 90;
    int s   = r / 90;            // 0..7
    int e   = xcd + ((s & 1) << 3);
    int mt  = s >> 1;            // 0..3
    int ne = counts[e];
    if (mt * 256 >= ne) return;

    int tid = threadIdx.x;
    int wave = tid >> 6, lane = tid & 63;
    int l16 = lane & 15, lq = lane >> 4;

    __shared__ int tokid[256];
    __shared__ unsigned short As[256 * 64];   // 32 KB
    __shared__ unsigned short Bs[64 * 64];    // 8 KB

    if (tid < 256) {
        int slot = mt * 256 + tid;
        tokid[tid] = (slot < ne) ? lists[e * T_TOK + slot] : lists[e * T_TOK];
    }
    __syncthreads();

    const float* gup_e = gup + (size_t)e * HDIM * GU_COLS;

    int at = tid - 256;
    const unsigned short* asrc[8];
    if (tid >= 256) {
#pragma unroll
        for (int i = 0; i < 8; ++i) {
            int s2 = at + i * 256;
            int row = s2 >> 3, c = s2 & 7;
            asrc[i] = xb + (size_t)tokid[row] * HDIM + ((c ^ (row & 7)) * 8);
        }
    }
    int nb = tid & 15, kb = tid >> 4;
    const float* bsrc = nullptr;
    if (tid < 256) {
        int n0 = nb * 4;
        size_t col = (n0 < 32) ? (size_t)(nt * 32 + n0) : (size_t)(IDIM + nt * 32 + (n0 - 32));
        bsrc = gup_e + (size_t)(kb * 4) * GU_COLS + col;
    }

    f32x4 acc[2][4];
#pragma unroll
    for (int i = 0; i < 2; ++i)
#pragma unroll
        for (int f = 0; f < 4; ++f) acc[i][f] = (f32x4){0.f, 0.f, 0.f, 0.f};

    float4 br0, br1, br2, br3;
    if (tid < 256) {
        br0 = *(const float4*)(bsrc);
        br1 = *(const float4*)(bsrc + GU_COLS);
        br2 = *(const float4*)(bsrc + 2 * GU_COLS);
        br3 = *(const float4*)(bsrc + 3 * GU_COLS);
    }

    for (int kk = 0; kk < HDIM; kk += 64) {
        __syncthreads();
        if (tid >= 256) {
#pragma unroll
            for (int i = 0; i < 8; ++i)
                gload16(asrc[i] + kk, As + ((size_t)(at + i * 256)) * 8);
        } else {
#pragma unroll
            for (int j = 0; j < 4; ++j) {
                int n = nb * 4 + j;
                int slot = kb ^ (n & 15);
                ushort4v b;
                b.x = f2b((&br0.x)[j]); b.y = f2b((&br1.x)[j]);
                b.z = f2b((&br2.x)[j]); b.w = f2b((&br3.x)[j]);
                *(ushort4v*)&Bs[n * 64 + slot * 4] = b;
            }
        }
        __syncthreads();
        if (tid < 256 && kk + 64 < HDIM) {
            const float* sp = bsrc + (size_t)(kk + 64) * GU_COLS;
            br0 = *(const float4*)(sp);
            br1 = *(const float4*)(sp + GU_COLS);
            br2 = *(const float4*)(sp + 2 * GU_COLS);
            br3 = *(const float4*)(sp + 3 * GU_COLS);
        }
        __builtin_amdgcn_s_setprio(1);
#pragma unroll
        for (int ks = 0; ks < 2; ++ks) {
            short8 a[2], b[4];
#pragma unroll
            for (int i = 0; i < 2; ++i) {
                int row = wave * 32 + i * 16 + l16;
                int q = ks * 4 + lq;
                a[i] = *(const short8*)&As[row * 64 + ((q ^ (row & 7)) * 8)];
            }
#pragma unroll
            for (int f = 0; f < 4; ++f) {
                int n = f * 16 + l16;
                int u0 = (ks * 8 + lq * 2) ^ (n & 15);
                int u1 = (ks * 8 + lq * 2 + 1) ^ (n & 15);
                short4v h0 = *(const short4v*)&Bs[n * 64 + u0 * 4];
                short4v h1 = *(const short4v*)&Bs[n * 64 + u1 * 4];
                b[f] = __builtin_shufflevector(h0, h1, 0, 1, 2, 3, 4, 5, 6, 7);
            }
#pragma unroll
            for (int i = 0; i < 2; ++i)
#pragma unroll
                for (int f = 0; f < 4; ++f)
                    acc[i][f] = __builtin_amdgcn_mfma_f32_16x16x32_bf16(a[i], b[f], acc[i][f], 0, 0, 0);
        }
        __builtin_amdgcn_s_setprio(0);
    }

    int off = prefix_off(counts, e);
    const float* gbe = gub + (size_t)e * GU_COLS;
#pragma unroll
    for (int j = 0; j < 2; ++j) {
        int col = j * 16 + l16;
        float bg = gbe[nt * 32 + col];
        float bu = gbe[IDIM + nt * 32 + col];
#pragma unroll
        for (int i = 0; i < 2; ++i)
#pragma unroll
            for (int r2 = 0; r2 < 4; ++r2) {
                int row = wave * 32 + i * 16 + lq * 4 + r2;
                int slot = mt * 256 + row;
                if (slot < ne) {
                    float g = acc[i][j][r2] + bg;
                    float u = acc[i][j + 2][r2] + bu;
                    float sg = g / (1.f + expf(-g));
                    inter[(size_t)(off + slot) * IDIM + nt * 32 + col] = f2b(sg * u);
                }
            }
    }
}

// ---------------- Kernel 4: down GEMM -> eo (bf16, atomic-free) ------------
__global__ __launch_bounds__(512) void down_kernel(
    const unsigned short* __restrict__ inter, const float* __restrict__ dw,
    const float* __restrict__ db, const int* __restrict__ counts,
    unsigned short* __restrict__ eo)
{
    int bid = blockIdx.x;
    int xcd = bid & 7;
    int r   = bid >> 3;          // 0..127
    int ht  = r & 15;
    int s   = r >> 4;            // 0..7
    int e   = xcd + ((s & 1) << 3);
    int mt  = s >> 1;            // 0..3
    int ne = counts[e];
    if (mt * 256 >= ne) return;

    int tid = threadIdx.x;
    int wave = tid >> 6, lane = tid & 63;
    int l16 = lane & 15, lq = lane >> 4;

    __shared__ unsigned short As[256 * 64];   // 32 KB
    __shared__ unsigned short Bs[64 * 64];    // 8 KB

    int off = prefix_off(counts, e);

    const float* dw_e = dw + (size_t)e * IDIM * HDIM;

    int at = tid - 256;
    const unsigned short* asrc[8];
    if (tid >= 256) {
#pragma unroll
        for (int i = 0; i < 8; ++i) {
            int s2 = at + i * 256;
            int row = s2 >> 3, c = s2 & 7;
            int slotr = mt * 256 + row; if (slotr >= ne) slotr = ne - 1;
            asrc[i] = inter + (size_t)(off + slotr) * IDIM + ((c ^ (row & 7)) * 8);
        }
    }
    int nb = tid & 15, kb = tid >> 4;
    const float* bsrc = nullptr;
    if (tid < 256)
        bsrc = dw_e + (size_t)(kb * 4) * HDIM + ht * 64 + nb * 4;

    f32x4 acc[2][4];
#pragma unroll
    for (int i = 0; i < 2; ++i)
#pragma unroll
        for (int f = 0; f < 4; ++f) acc[i][f] = (f32x4){0.f, 0.f, 0.f, 0.f};

    float4 br0, br1, br2, br3;
    if (tid < 256) {
        br0 = *(const float4*)(bsrc);
        br1 = *(const float4*)(bsrc + HDIM);
        br2 = *(const float4*)(bsrc + 2 * HDIM);
        br3 = *(const float4*)(bsrc + 3 * HDIM);
    }

    for (int kk = 0; kk < IDIM; kk += 64) {
        __syncthreads();
        if (tid >= 256) {
#pragma unroll
            for (int i = 0; i < 8; ++i)
                gload16(asrc[i] + kk, As + ((size_t)(at + i * 256)) * 8);
        } else {
#pragma unroll
            for (int j = 0; j < 4; ++j) {
                int n = nb * 4 + j;
                int slot = kb ^ (n & 15);
                ushort4v b;
                b.x = f2b((&br0.x)[j]); b.y = f2b((&br1.x)[j]);
                b.z = f2b((&br2.x)[j]); b.w = f2b((&br3.x)[j]);
                *(ushort4v*)&Bs[n * 64 + slot * 4] = b;
            }
        }
        __syncthreads();
        if (tid < 256 && kk + 64 < IDIM) {
            const float* sp = bsrc + (size_t)(kk + 64) * HDIM;
            br0 = *(const float4*)(sp);
            br1 = *(const float4*)(sp + HDIM);
            br2 = *(const float4*)(sp + 2 * HDIM);
            br3 = *(const float4*)(sp + 3 * HDIM);
        }
        __builtin_amdgcn_s_setprio(1);
#pragma unroll
        for (int ks = 0; ks < 2; ++ks) {
            short8 a[2], b[4];
#pragma unroll
            for (int i = 0; i < 2; ++i) {
                int row = wave * 32 + i * 16 + l16;
                int q = ks * 4 + lq;
                a[i] = *(const short8*)&As[row * 64 + ((q ^ (row & 7)) * 8)];
            }
#pragma unroll
            for (int f = 0; f < 4; ++f) {
                int n = f * 16 + l16;
                int u0 = (ks * 8 + lq * 2) ^ (n & 15);
                int u1 = (ks * 8 + lq * 2 + 1) ^ (n & 15);
                short4v h0 = *(const short4v*)&Bs[n * 64 + u0 * 4];
                short4v h1 = *(const short4v*)&Bs[n * 64 + u1 * 4];
                b[f] = __builtin_shufflevector(h0, h1, 0, 1, 2, 3, 4, 5, 6, 7);
            }
#pragma unroll
            for (int i = 0; i < 2; ++i)
#pragma unroll
                for (int f = 0; f < 4; ++f)
                    acc[i][f] = __builtin_amdgcn_mfma_f32_16x16x32_bf16(a[i], b[f], acc[i][f], 0, 0, 0);
        }
        __builtin_amdgcn_s_setprio(0);
    }

    const float* db_e = db + (size_t)e * HDIM;
#pragma unroll
    for (int f = 0; f < 4; ++f) {
        int h = ht * 64 + f * 16 + l16;
        float bias = db_e[h];
#pragma unroll
        for (int i = 0; i < 2; ++i)
#pragma unroll
            for (int r2 = 0; r2 < 4; ++r2) {
                int row = wave * 32 + i * 16 + lq * 4 + r2;
                int slot = mt * 256 + row;
                if (slot < ne)
                    eo[(size_t)(off + slot) * HDIM + h] = f2b(acc[i][f][r2] + bias);
            }
    }
}

// ---------------- Kernel 5: weighted gather (bf16 eo) ----------------------
__global__ __launch_bounds__(256) void gather_kernel(
    const unsigned short* __restrict__ eo, const int* __restrict__ tokslot4,
    const float* __restrict__ wts4, const int* __restrict__ counts,
    float* __restrict__ out)
{
    int t = blockIdx.x;
    int tid = threadIdx.x;
    int offs[NEXP];
    {
        int o = 0;
#pragma unroll
        for (int i = 0; i < NEXP; ++i) { offs[i] = o; o += counts[i]; }
    }
    int rows[TOPK]; float w[TOPK];
#pragma unroll
    for (int k = 0; k < TOPK; ++k) {
        int ts = tokslot4[t * TOPK + k];
        int e = ts >> 16, slot = ts & 0xFFFF;
        rows[k] = offs[e] + slot;
        w[k] = wts4[t * TOPK + k];
    }
    int h0 = tid * 4;
    float4 s = make_float4(0.f, 0.f, 0.f, 0.f);
#pragma unroll
    for (int k = 0; k < TOPK; ++k) {
        ushort4v v = *(const ushort4v*)(eo + (size_t)rows[k] * HDIM + h0);
        s.x += w[k] * b2f(v.x); s.y += w[k] * b2f(v.y);
        s.z += w[k] * b2f(v.z); s.w += w[k] * b2f(v.w);
    }
    *(float4*)(out + (size_t)t * HDIM + h0) = s;
}

// ---------------------------------------------------------------------------
extern "C" void kernel_launch(void* const* d_in, const int* in_sizes, int n_in,
                              void* d_out, int out_size, void* d_ws, size_t ws_size,
                              hipStream_t stream)
{
    const float* x   = (const float*)d_in[0];
    const float* gw  = (const float*)d_in[1];
    const float* gb  = (const float*)d_in[2];
    const float* gup = (const float*)d_in[3];
    const float* gub = (const float*)d_in[4];
    const float* dw  = (const float*)d_in[5];
    const float* db  = (const float*)d_in[6];

    float* out        = (float*)d_out;
    float* logits_out = out + (size_t)T_TOK * HDIM;

    char* ws = (char*)d_ws;
    int*   counts   = (int*)(ws + 0);
    int*   lists    = (int*)(ws + 512);                       // 64 KB
    float* wts      = (float*)(ws + 512 + 65536);             // 64 KB
    int*   tokslot4 = (int*)(ws + 512 + 131072);              // 16 KB
    float* wts4     = (float*)(ws + 512 + 131072 + 16384);    // 16 KB
    unsigned short* xb    = (unsigned short*)(ws + 164352);   // 2 MB
    unsigned short* inter = (unsigned short*)(ws + 2261504);  // 23.6 MB
    unsigned short* eo    = (unsigned short*)(ws + 25854464); // 8.4 MB (bf16)

    hipMemsetAsync(counts, 0, 64, stream);

    router_kernel<<<T_TOK, 256, 0, stream>>>(x, gw, gb, logits_out, counts, lists, wts, tokslot4, wts4, xb);
    gu_kernel<<<8 * 90 * 8, 512, 0, stream>>>(xb, gup, gub, counts, lists, inter);
    down_kernel<<<8 * 16 * 8, 512, 0, stream>>>(inter, dw, db, counts, eo);
    gather_kernel<<<T_TOK, 256, 0, stream>>>(eo, tokslot4, wts4, counts, out);
}

// Round 24
// 300.516 us; speedup vs baseline: 1.0667x; 1.0003x over previous
//
#include <hip/hip_runtime.h>
#include <hip/hip_bf16.h>
#include <stdint.h>

#define T_TOK 1024
#define HDIM  1024
#define NEXP  16
#define IDIM  2880
#define GU_COLS (2*IDIM)   // 5760
#define TOPK  4

using short4v  = __attribute__((ext_vector_type(4))) short;
using short8   = __attribute__((ext_vector_type(8))) short;
using ushort4v = __attribute__((ext_vector_type(4))) unsigned short;
using f32x4    = __attribute__((ext_vector_type(4))) float;

__device__ __forceinline__ unsigned short f2b(float f) {
    union { float f; unsigned u; } x; x.f = f;
    unsigned r = x.u + 0x7FFFu + ((x.u >> 16) & 1u);  // RNE
    return (unsigned short)(r >> 16);
}
__device__ __forceinline__ float b2f(unsigned short b) {
    union { unsigned u; float f; } x; x.u = ((unsigned)b) << 16;
    return x.f;
}

typedef const __attribute__((address_space(1))) unsigned int* gas1_t;
typedef __attribute__((address_space(3))) unsigned int* las3_t;
__device__ __forceinline__ void gload16(const void* g, void* l) {
    __builtin_amdgcn_global_load_lds((gas1_t)g, (las3_t)l, 16, 0, 0);
}

// in-kernel exclusive prefix over counts[0..NEXP) up to e
__device__ __forceinline__ int prefix_off(const int* __restrict__ counts, int e) {
    int o = 0;
#pragma unroll
    for (int i = 0; i < NEXP; ++i)
        if (i < e) o += counts[i];
    return o;
}

// ---------------- Kernel 1: router + x->bf16 --------------------------------
__global__ __launch_bounds__(256) void router_kernel(
    const float* __restrict__ x, const float* __restrict__ gw,
    const float* __restrict__ gb, float* __restrict__ logits_out,
    int* __restrict__ counts, int* __restrict__ lists,
    int* __restrict__ tokslot4, float* __restrict__ wts4,
    unsigned short* __restrict__ xb)
{
    int t = blockIdx.x;
    int tid = threadIdx.x;
    const float* xr = x + (size_t)t * HDIM;
    {
        float4 v = *(const float4*)(xr + tid * 4);
        ushort4v b; b.x = f2b(v.x); b.y = f2b(v.y); b.z = f2b(v.z); b.w = f2b(v.w);
        *(ushort4v*)(xb + (size_t)t * HDIM + tid * 4) = b;
    }
    int e = tid >> 4;
    int l16 = tid & 15;
    const float* wr = gw + (size_t)e * HDIM;
    float p = 0.f;
    for (int h = l16; h < HDIM; h += 16) p += xr[h] * wr[h];
    p += __shfl_xor(p, 8);
    p += __shfl_xor(p, 4);
    p += __shfl_xor(p, 2);
    p += __shfl_xor(p, 1);
    __shared__ float sl[NEXP];
    if (l16 == 0) {
        float v = p + gb[e];
        sl[e] = v;
        logits_out[t * NEXP + e] = v;
    }
    __syncthreads();
    if (tid == 0) {
        float v[NEXP];
#pragma unroll
        for (int i = 0; i < NEXP; ++i) v[i] = sl[i];
        int idx[TOPK]; float tv[TOPK];
        unsigned used = 0;
#pragma unroll
        for (int k = 0; k < TOPK; ++k) {
            float best = -__builtin_inff(); int bi = 0;
#pragma unroll
            for (int i = 0; i < NEXP; ++i)
                if (!((used >> i) & 1u) && v[i] > best) { best = v[i]; bi = i; }
            used |= 1u << bi; idx[k] = bi; tv[k] = best;
        }
        float m = tv[0];
        float ex[TOPK], s = 0.f;
#pragma unroll
        for (int k = 0; k < TOPK; ++k) { ex[k] = expf(tv[k] - m); s += ex[k]; }
#pragma unroll
        for (int k = 0; k < TOPK; ++k) {
            float w = ex[k] / s;
            int slot = atomicAdd(&counts[idx[k]], 1);
            lists[idx[k] * T_TOK + slot] = t;
            tokslot4[t * TOPK + k] = (idx[k] << 16) | slot;
            wts4[t * TOPK + k] = w;
        }
    }
}

// ---------------- Kernel 3: gate_up GEMM + silu ----------------------------
__global__ __launch_bounds__(512) void gu_kernel(
    const unsigned short* __restrict__ xb, const float* __restrict__ gup,
    const float* __restrict__ gub, const int* __restrict__ counts,
    const int* __restrict__ lists, unsigned short* __restrict__ inter)
{
    int bid = blockIdx.x;
    int xcd = bid & 7;
    int r   = bid >> 3;          // 0..719
    int nt  = r % 90;
    int s   = r / 90;            // 0..7
    int e   = xcd + ((s & 1) << 3);
    int mt  = s >> 1;            // 0..3
    int ne = counts[e];
    if (mt * 256 >= ne) return;

    int tid = threadIdx.x;
    int wave = tid >> 6, lane = tid & 63;
    int l16 = lane & 15, lq = lane >> 4;

    __shared__ int tokid[256];
    __shared__ unsigned short As[256 * 64];   // 32 KB
    __shared__ unsigned short Bs[64 * 64];    // 8 KB

    if (tid < 256) {
        int slot = mt * 256 + tid;
        tokid[tid] = (slot < ne) ? lists[e * T_TOK + slot] : lists[e * T_TOK];
    }
    __syncthreads();

    const float* gup_e = gup + (size_t)e * HDIM * GU_COLS;

    int at = tid - 256;
    const unsigned short* asrc[8];
    if (tid >= 256) {
#pragma unroll
        for (int i = 0; i < 8; ++i) {
            int s2 = at + i * 256;
            int row = s2 >> 3, c = s2 & 7;
            asrc[i] = xb + (size_t)tokid[row] * HDIM + ((c ^ (row & 7)) * 8);
        }
    }
    int nb = tid & 15, kb = tid >> 4;
    const float* bsrc = nullptr;
    if (tid < 256) {
        int n0 = nb * 4;
        size_t col = (n0 < 32) ? (size_t)(nt * 32 + n0) : (size_t)(IDIM + nt * 32 + (n0 - 32));
        bsrc = gup_e + (size_t)(kb * 4) * GU_COLS + col;
    }

    f32x4 acc[2][4];
#pragma unroll
    for (int i = 0; i < 2; ++i)
#pragma unroll
        for (int f = 0; f < 4; ++f) acc[i][f] = (f32x4){0.f, 0.f, 0.f, 0.f};

    float4 br0, br1, br2, br3;
    if (tid < 256) {
        br0 = *(const float4*)(bsrc);
        br1 = *(const float4*)(bsrc + GU_COLS);
        br2 = *(const float4*)(bsrc + 2 * GU_COLS);
        br3 = *(const float4*)(bsrc + 3 * GU_COLS);
    }

    for (int kk = 0; kk < HDIM; kk += 64) {
        __syncthreads();
        if (tid >= 256) {
#pragma unroll
            for (int i = 0; i < 8; ++i)
                gload16(asrc[i] + kk, As + ((size_t)(at + i * 256)) * 8);
        } else {
#pragma unroll
            for (int j = 0; j < 4; ++j) {
                int n = nb * 4 + j;
                int slot = kb ^ (n & 15);
                ushort4v b;
                b.x = f2b((&br0.x)[j]); b.y = f2b((&br1.x)[j]);
                b.z = f2b((&br2.x)[j]); b.w = f2b((&br3.x)[j]);
                *(ushort4v*)&Bs[n * 64 + slot * 4] = b;
            }
        }
        __syncthreads();
        if (tid < 256 && kk + 64 < HDIM) {
            const float* sp = bsrc + (size_t)(kk + 64) * GU_COLS;
            br0 = *(const float4*)(sp);
            br1 = *(const float4*)(sp + GU_COLS);
            br2 = *(const float4*)(sp + 2 * GU_COLS);
            br3 = *(const float4*)(sp + 3 * GU_COLS);
        }
        __builtin_amdgcn_s_setprio(1);
#pragma unroll
        for (int ks = 0; ks < 2; ++ks) {
            short8 a[2], b[4];
#pragma unroll
            for (int i = 0; i < 2; ++i) {
                int row = wave * 32 + i * 16 + l16;
                int q = ks * 4 + lq;
                a[i] = *(const short8*)&As[row * 64 + ((q ^ (row & 7)) * 8)];
            }
#pragma unroll
            for (int f = 0; f < 4; ++f) {
                int n = f * 16 + l16;
                int u0 = (ks * 8 + lq * 2) ^ (n & 15);
                int u1 = (ks * 8 + lq * 2 + 1) ^ (n & 15);
                short4v h0 = *(const short4v*)&Bs[n * 64 + u0 * 4];
                short4v h1 = *(const short4v*)&Bs[n * 64 + u1 * 4];
                b[f] = __builtin_shufflevector(h0, h1, 0, 1, 2, 3, 4, 5, 6, 7);
            }
#pragma unroll
            for (int i = 0; i < 2; ++i)
#pragma unroll
                for (int f = 0; f < 4; ++f)
                    acc[i][f] = __builtin_amdgcn_mfma_f32_16x16x32_bf16(a[i], b[f], acc[i][f], 0, 0, 0);
        }
        __builtin_amdgcn_s_setprio(0);
    }

    int off = prefix_off(counts, e);
    const float* gbe = gub + (size_t)e * GU_COLS;
#pragma unroll
    for (int j = 0; j < 2; ++j) {
        int col = j * 16 + l16;
        float bg = gbe[nt * 32 + col];
        float bu = gbe[IDIM + nt * 32 + col];
#pragma unroll
        for (int i = 0; i < 2; ++i)
#pragma unroll
            for (int r2 = 0; r2 < 4; ++r2) {
                int row = wave * 32 + i * 16 + lq * 4 + r2;
                int slot = mt * 256 + row;
                if (slot < ne) {
                    float g = acc[i][j][r2] + bg;
                    float u = acc[i][j + 2][r2] + bu;
                    float sg = g / (1.f + expf(-g));
                    inter[(size_t)(off + slot) * IDIM + nt * 32 + col] = f2b(sg * u);
                }
            }
    }
}

// ---------------- Kernel 4: down GEMM -> eo (bf16, atomic-free) ------------
__global__ __launch_bounds__(512) void down_kernel(
    const unsigned short* __restrict__ inter, const float* __restrict__ dw,
    const float* __restrict__ db, const int* __restrict__ counts,
    unsigned short* __restrict__ eo)
{
    int bid = blockIdx.x;
    int xcd = bid & 7;
    int r   = bid >> 3;          // 0..127
    int ht  = r & 15;
    int s   = r >> 4;            // 0..7
    int e   = xcd + ((s & 1) << 3);
    int mt  = s >> 1;            // 0..3
    int ne = counts[e];
    if (mt * 256 >= ne) return;

    int tid = threadIdx.x;
    int wave = tid >> 6, lane = tid & 63;
    int l16 = lane & 15, lq = lane >> 4;

    __shared__ unsigned short As[256 * 64];   // 32 KB
    __shared__ unsigned short Bs[64 * 64];    // 8 KB

    int off = prefix_off(counts, e);

    const float* dw_e = dw + (size_t)e * IDIM * HDIM;

    int at = tid - 256;
    const unsigned short* asrc[8];
    if (tid >= 256) {
#pragma unroll
        for (int i = 0; i < 8; ++i) {
            int s2 = at + i * 256;
            int row = s2 >> 3, c = s2 & 7;
            int slotr = mt * 256 + row; if (slotr >= ne) slotr = ne - 1;
            asrc[i] = inter + (size_t)(off + slotr) * IDIM + ((c ^ (row & 7)) * 8);
        }
    }
    int nb = tid & 15, kb = tid >> 4;
    const float* bsrc = nullptr;
    if (tid < 256)
        bsrc = dw_e + (size_t)(kb * 4) * HDIM + ht * 64 + nb * 4;

    f32x4 acc[2][4];
#pragma unroll
    for (int i = 0; i < 2; ++i)
#pragma unroll
        for (int f = 0; f < 4; ++f) acc[i][f] = (f32x4){0.f, 0.f, 0.f, 0.f};

    float4 br0, br1, br2, br3;
    if (tid < 256) {
        br0 = *(const float4*)(bsrc);
        br1 = *(const float4*)(bsrc + HDIM);
        br2 = *(const float4*)(bsrc + 2 * HDIM);
        br3 = *(const float4*)(bsrc + 3 * HDIM);
    }

    for (int kk = 0; kk < IDIM; kk += 64) {
        __syncthreads();
        if (tid >= 256) {
#pragma unroll
            for (int i = 0; i < 8; ++i)
                gload16(asrc[i] + kk, As + ((size_t)(at + i * 256)) * 8);
        } else {
#pragma unroll
            for (int j = 0; j < 4; ++j) {
                int n = nb * 4 + j;
                int slot = kb ^ (n & 15);
                ushort4v b;
                b.x = f2b((&br0.x)[j]); b.y = f2b((&br1.x)[j]);
                b.z = f2b((&br2.x)[j]); b.w = f2b((&br3.x)[j]);
                *(ushort4v*)&Bs[n * 64 + slot * 4] = b;
            }
        }
        __syncthreads();
        if (tid < 256 && kk + 64 < IDIM) {
            const float* sp = bsrc + (size_t)(kk + 64) * HDIM;
            br0 = *(const float4*)(sp);
            br1 = *(const float4*)(sp + HDIM);
            br2 = *(const float4*)(sp + 2 * HDIM);
            br3 = *(const float4*)(sp + 3 * HDIM);
        }
        __builtin_amdgcn_s_setprio(1);
#pragma unroll
        for (int ks = 0; ks < 2; ++ks) {
            short8 a[2], b[4];
#pragma unroll
            for (int i = 0; i < 2; ++i) {
                int row = wave * 32 + i * 16 + l16;
                int q = ks * 4 + lq;
                a[i] = *(const short8*)&As[row * 64 + ((q ^ (row & 7)) * 8)];
            }
#pragma unroll
            for (int f = 0; f < 4; ++f) {
                int n = f * 16 + l16;
                int u0 = (ks * 8 + lq * 2) ^ (n & 15);
                int u1 = (ks * 8 + lq * 2 + 1) ^ (n & 15);
                short4v h0 = *(const short4v*)&Bs[n * 64 + u0 * 4];
                short4v h1 = *(const short4v*)&Bs[n * 64 + u1 * 4];
                b[f] = __builtin_shufflevector(h0, h1, 0, 1, 2, 3, 4, 5, 6, 7);
            }
#pragma unroll
            for (int i = 0; i < 2; ++i)
#pragma unroll
                for (int f = 0; f < 4; ++f)
                    acc[i][f] = __builtin_amdgcn_mfma_f32_16x16x32_bf16(a[i], b[f], acc[i][f], 0, 0, 0);
        }
        __builtin_amdgcn_s_setprio(0);
    }

    const float* db_e = db + (size_t)e * HDIM;
#pragma unroll
    for (int f = 0; f < 4; ++f) {
        int h = ht * 64 + f * 16 + l16;
        float bias = db_e[h];
#pragma unroll
        for (int i = 0; i < 2; ++i)
#pragma unroll
            for (int r2 = 0; r2 < 4; ++r2) {
                int row = wave * 32 + i * 16 + lq * 4 + r2;
                int slot = mt * 256 + row;
                if (slot < ne)
                    eo[(size_t)(off + slot) * HDIM + h] = f2b(acc[i][f][r2] + bias);
            }
    }
}

// ---------------- Kernel 5: weighted gather (bf16 eo) ----------------------
__global__ __launch_bounds__(256) void gather_kernel(
    const unsigned short* __restrict__ eo, const int* __restrict__ tokslot4,
    const float* __restrict__ wts4, const int* __restrict__ counts,
    float* __restrict__ out)
{
    int t = blockIdx.x;
    int tid = threadIdx.x;
    int offs[NEXP];
    {
        int o = 0;
#pragma unroll
        for (int i = 0; i < NEXP; ++i) { offs[i] = o; o += counts[i]; }
    }
    int rows[TOPK]; float w[TOPK];
#pragma unroll
    for (int k = 0; k < TOPK; ++k) {
        int ts = tokslot4[t * TOPK + k];
        int e = ts >> 16, slot = ts & 0xFFFF;
        rows[k] = offs[e] + slot;
        w[k] = wts4[t * TOPK + k];
    }
    int h0 = tid * 4;
    float4 s = make_float4(0.f, 0.f, 0.f, 0.f);
#pragma unroll
    for (int k = 0; k < TOPK; ++k) {
        ushort4v v = *(const ushort4v*)(eo + (size_t)rows[k] * HDIM + h0);
        s.x += w[k] * b2f(v.x); s.y += w[k] * b2f(v.y);
        s.z += w[k] * b2f(v.z); s.w += w[k] * b2f(v.w);
    }
    *(float4*)(out + (size_t)t * HDIM + h0) = s;
}

// ---------------------------------------------------------------------------
extern "C" void kernel_launch(void* const* d_in, const int* in_sizes, int n_in,
                              void* d_out, int out_size, void* d_ws, size_t ws_size,
                              hipStream_t stream)
{
    const float* x   = (const float*)d_in[0];
    const float* gw  = (const float*)d_in[1];
    const float* gb  = (const float*)d_in[2];
    const float* gup = (const float*)d_in[3];
    const float* gub = (const float*)d_in[4];
    const float* dw  = (const float*)d_in[5];
    const float* db  = (const float*)d_in[6];

    float* out        = (float*)d_out;
    float* logits_out = out + (size_t)T_TOK * HDIM;

    char* ws = (char*)d_ws;
    int*   counts   = (int*)(ws + 0);
    int*   lists    = (int*)(ws + 512);                       // 64 KB
    int*   tokslot4 = (int*)(ws + 512 + 65536);               // 16 KB
    float* wts4     = (float*)(ws + 512 + 65536 + 16384);     // 16 KB
    unsigned short* xb    = (unsigned short*)(ws + 131584);   // 2 MB
    unsigned short* inter = (unsigned short*)(ws + 2228736);  // 23.6 MB
    unsigned short* eo    = (unsigned short*)(ws + 25821696); // 8.4 MB (bf16)

    hipMemsetAsync(counts, 0, 64, stream);

    router_kernel<<<T_TOK, 256, 0, stream>>>(x, gw, gb, logits_out, counts, lists, tokslot4, wts4, xb);
    gu_kernel<<<8 * 90 * 8, 512, 0, stream>>>(xb, gup, gub, counts, lists, inter);
    down_kernel<<<8 * 16 * 8, 512, 0, stream>>>(inter, dw, db, counts, eo);
    gather_kernel<<<T_TOK, 256, 0, stream>>>(eo, tokslot4, wts4, counts, out);
}